// Round 6
// baseline (1573.205 us; speedup 1.0000x reference)
//
#include <hip/hip_runtime.h>

typedef unsigned short u16;
typedef unsigned int u32;
typedef __attribute__((ext_vector_type(8))) short bf16x8;
typedef __attribute__((ext_vector_type(4))) float f32x4;

#define SEQ 1024
#define DM 768
#define NH 12
#define HD2 64
#define NLAYER 4
#define NVOCAB 50257
#define BT 2048  // B*T

__device__ __forceinline__ u16 f2bf(float f) {
  union { float f; u32 u; } v; v.f = f;
  u32 r = v.u + 0x7FFFu + ((v.u >> 16) & 1u);
  return (u16)(r >> 16);
}
__device__ __forceinline__ float bf2f(u16 u) {
  union { u32 u; float f; } v; v.u = ((u32)u) << 16;
  return v.f;
}

__device__ __forceinline__ void glds16(const u16* g, u16* l) {
  __builtin_amdgcn_global_load_lds(
      (const __attribute__((address_space(1))) u32*)(const void*)g,
      (__attribute__((address_space(3))) u32*)(void*)l, 16, 0, 0);
}

// ---------------- embedding ----------------
__global__ void k_embed(const int* __restrict__ idx, const float* __restrict__ wte,
                        float* __restrict__ xf) {
  int r = blockIdx.x;
  int tok = idx[r];
  const float* s = wte + (size_t)tok * DM;
  float* d = xf + (size_t)r * DM;
  for (int c = threadIdx.x; c < DM; c += 256) d[c] = s[c];
}

// ------- transpose + f32->bf16: in[R,C] f32 -> out[C,R] bf16 (64x64 tile) ----
__global__ void k_cvtT(const float* __restrict__ in, u16* __restrict__ out,
                       int R, int C) {
  __shared__ u16 t[64][68];
  int c0 = blockIdx.x * 64, r0 = blockIdx.y * 64;  // R always multiple of 64
  int tx = threadIdx.x & 15, ty = threadIdx.x >> 4;
  int c = c0 + tx * 4;
#pragma unroll
  for (int i = 0; i < 4; ++i) {
    int r = r0 + ty + i * 16;
    float4 v = make_float4(0.f, 0.f, 0.f, 0.f);
    if (c + 3 < C) {
      v = *(const float4*)&in[(size_t)r * C + c];
    } else {
      if (c + 0 < C) v.x = in[(size_t)r * C + c];
      if (c + 1 < C) v.y = in[(size_t)r * C + c + 1];
      if (c + 2 < C) v.z = in[(size_t)r * C + c + 2];
      if (c + 3 < C) v.w = in[(size_t)r * C + c + 3];
    }
    t[ty + i * 16][tx * 4 + 0] = f2bf(v.x);
    t[ty + i * 16][tx * 4 + 1] = f2bf(v.y);
    t[ty + i * 16][tx * 4 + 2] = f2bf(v.z);
    t[ty + i * 16][tx * 4 + 3] = f2bf(v.w);
  }
  __syncthreads();
  int wl = threadIdx.x & 31, grp = threadIdx.x >> 5;
#pragma unroll
  for (int it = 0; it < 8; ++it) {
    int cc = it * 8 + grp;
    int gcol = c0 + cc;
    if (gcol < C) {
      u32 wv = (u32)t[2 * wl][cc] | ((u32)t[2 * wl + 1][cc] << 16);
      *(u32*)&out[(size_t)gcol * R + r0 + 2 * wl] = wv;
    }
  }
}

// ---------------- block reductions (256 thr = 4 waves) ----------------
__device__ __forceinline__ float bsum(float v, float* red) {
#pragma unroll
  for (int o = 32; o > 0; o >>= 1) v += __shfl_down(v, o);
  if ((threadIdx.x & 63) == 0) red[threadIdx.x >> 6] = v;
  __syncthreads();
  if (threadIdx.x == 0) red[4] = red[0] + red[1] + red[2] + red[3];
  __syncthreads();
  return red[4];
}

// ---------------- dual layernorm (both read same x) ----------------
__global__ void k_ln(const float* __restrict__ x, const float* __restrict__ g1,
                     const float* __restrict__ b1, const float* __restrict__ g2,
                     const float* __restrict__ b2, u16* __restrict__ o1,
                     u16* __restrict__ o2) {
  __shared__ float red[8];
  int r = blockIdx.x;
  int t = threadIdx.x;
  const float* xr = x + (size_t)r * DM;
  float v0 = xr[t], v1 = xr[t + 256], v2 = xr[t + 512];
  float mean = bsum(v0 + v1 + v2, red) * (1.f / DM);
  float d0 = v0 - mean, d1 = v1 - mean, d2 = v2 - mean;
  float var = bsum(d0 * d0 + d1 * d1 + d2 * d2, red) * (1.f / DM);
  float rstd = rsqrtf(var + 1e-5f);
  u16* p1 = o1 + (size_t)r * DM;
  p1[t]       = f2bf(d0 * rstd * g1[t]       + b1[t]);
  p1[t + 256] = f2bf(d1 * rstd * g1[t + 256] + b1[t + 256]);
  p1[t + 512] = f2bf(d2 * rstd * g1[t + 512] + b1[t + 512]);
  if (o2) {
    u16* p2 = o2 + (size_t)r * DM;
    p2[t]       = f2bf(d0 * rstd * g2[t]       + b2[t]);
    p2[t + 256] = f2bf(d1 * rstd * g2[t + 256] + b2[t + 256]);
    p2[t + 512] = f2bf(d2 * rstd * g2[t + 512] + b2[t + 512]);
  }
}

// ---------------- partial RoPE on q,k ----------------
__global__ void k_rope(const u16* __restrict__ qkvb, u16* __restrict__ qr,
                       u16* __restrict__ kr) {
  int gid = blockIdx.x * 256 + threadIdx.x;  // over B*T*NH*32
  int j = gid & 31;
  int h = (gid >> 5) % NH;
  int t = (gid / (32 * NH)) & (SEQ - 1);
  int b = gid / (32 * NH * SEQ);
  float c = 1.f, s = 0.f;
  if (j < 16) {
    float inv = powf(10000.f, -(float)j * (1.f / 32.f));
    float ang = (float)t * inv;
    c = cosf(ang);
    s = sinf(ang);
  }
  size_t base = (size_t)(b * SEQ + t) * (3 * DM);
  size_t ob = ((size_t)(b * NH + h) * SEQ + t) * HD2 + j;
  {
    float a0 = bf2f(qkvb[base + h * HD2 + j]);
    float a1 = bf2f(qkvb[base + h * HD2 + j + 32]);
    qr[ob] = f2bf(a0 * c - a1 * s);
    qr[ob + 32] = f2bf(a1 * c + a0 * s);
  }
  {
    float a0 = bf2f(qkvb[base + DM + h * HD2 + j]);
    float a1 = bf2f(qkvb[base + DM + h * HD2 + j + 32]);
    kr[ob] = f2bf(a0 * c - a1 * s);
    kr[ob + 32] = f2bf(a1 * c + a0 * s);
  }
}

// ---------------- v transpose: [B,T,H,HD] slice -> [B,H,HD,T] ----------------
__global__ void k_vtrans(const u16* __restrict__ qkvb, u16* __restrict__ vT) {
  __shared__ u16 tile[64][65];
  int t0 = blockIdx.x * 64;
  int bh = blockIdx.y;
  int b = bh / NH, h = bh % NH;
  int rr = threadIdx.x >> 2, seg = threadIdx.x & 3;
  const u16* src = qkvb + (size_t)(b * SEQ + t0 + rr) * (3 * DM) + 2 * DM + h * HD2;
#pragma unroll
  for (int i = 0; i < 16; ++i) tile[rr][seg * 16 + i] = src[seg * 16 + i];
  __syncthreads();
  u16* dst = vT + ((size_t)bh * HD2 + rr) * SEQ + t0;
#pragma unroll
  for (int i = 0; i < 16; ++i) dst[seg * 16 + i] = tile[seg * 16 + i][rr];
}

// ---------------- fused flash attention, glds-staged double-buffered K/V ----
__global__ void k_attn(const u16* __restrict__ qr, const u16* __restrict__ kr,
                       const u16* __restrict__ vT, u16* __restrict__ yb) {
  int ti = (int)gridDim.x - 1 - (int)blockIdx.x;  // big tiles first
  int bh = blockIdx.y;
  __shared__ u16 Ps[64 * 72];       // Q staging, then P tile (wave-private rows)
  __shared__ u16 Ks[2][4096];       // [64][64] XOR-swizzled
  __shared__ u16 Vs[2][4096];
  int tid = threadIdx.x;
  int rr = tid >> 2, cc = tid & 3;
  int w = tid >> 6, l = tid & 63;
  int rl = l & 15, g = l >> 4;
  {
    const u16* gq = qr + ((size_t)bh * SEQ + ti * 64 + rr) * HD2;
    *(uint4*)&Ps[rr * 72 + cc * 8]      = *(const uint4*)(gq + cc * 8);
    *(uint4*)&Ps[rr * 72 + cc * 8 + 32] = *(const uint4*)(gq + cc * 8 + 32);
  }
  int srow = w * 8 + (l >> 3);
  int gs = (l & 7) ^ (l >> 3);
  const u16* gkb = kr + (size_t)bh * SEQ * HD2;
  const u16* gvb = vT + (size_t)bh * HD2 * SEQ;
  glds16(gkb + (size_t)srow * 64 + gs * 8,        &Ks[0][w * 512]);
  glds16(gkb + (size_t)(32 + srow) * 64 + gs * 8, &Ks[0][2048 + w * 512]);
  glds16(gvb + (size_t)srow * SEQ + gs * 8,       &Vs[0][w * 512]);
  glds16(gvb + (size_t)(32 + srow) * SEQ + gs * 8,&Vs[0][2048 + w * 512]);
  __syncthreads();
  bf16x8 aq0 = *(const bf16x8*)&Ps[(w * 16 + rl) * 72 + g * 8];
  bf16x8 aq1 = *(const bf16x8*)&Ps[(w * 16 + rl) * 72 + 32 + g * 8];
  float m[4], lsum[4];
  f32x4 oacc[4] = {};
#pragma unroll
  for (int r2 = 0; r2 < 4; ++r2) { m[r2] = -3.0e38f; lsum[r2] = 0.f; }
  int qloc = w * 16 + g * 4;
  int sw = rl & 7;
  int cur = 0;
  for (int kt = 0; kt <= ti; ++kt) {
    if (kt < ti) {
      int nx = cur ^ 1;
      glds16(gkb + (size_t)((kt + 1) * 64 + srow) * 64 + gs * 8,      &Ks[nx][w * 512]);
      glds16(gkb + (size_t)((kt + 1) * 64 + 32 + srow) * 64 + gs * 8, &Ks[nx][2048 + w * 512]);
      glds16(gvb + (size_t)srow * SEQ + (kt + 1) * 64 + gs * 8,       &Vs[nx][w * 512]);
      glds16(gvb + (size_t)(32 + srow) * SEQ + (kt + 1) * 64 + gs * 8,&Vs[nx][2048 + w * 512]);
    }
    f32x4 s[4] = {};
    __builtin_amdgcn_s_setprio(1);
#pragma unroll
    for (int nt = 0; nt < 4; ++nt) {
      int r = (nt * 16 + rl) * 64;
      bf16x8 b0 = *(const bf16x8*)&Ks[cur][r + ((0 + g) ^ sw) * 8];
      bf16x8 b1 = *(const bf16x8*)&Ks[cur][r + ((4 + g) ^ sw) * 8];
      s[nt] = __builtin_amdgcn_mfma_f32_16x16x32_bf16(aq0, b0, s[nt], 0, 0, 0);
      s[nt] = __builtin_amdgcn_mfma_f32_16x16x32_bf16(aq1, b1, s[nt], 0, 0, 0);
    }
    __builtin_amdgcn_s_setprio(0);
#pragma unroll
    for (int nt = 0; nt < 4; ++nt) s[nt] *= 0.125f;
    if (kt == ti) {
#pragma unroll
      for (int nt = 0; nt < 4; ++nt) {
        int col = nt * 16 + rl;
#pragma unroll
        for (int r2 = 0; r2 < 4; ++r2)
          if (col > qloc + r2) s[nt][r2] = -3.0e38f;
      }
    }
#pragma unroll
    for (int r2 = 0; r2 < 4; ++r2) {
      float pm = fmaxf(fmaxf(s[0][r2], s[1][r2]), fmaxf(s[2][r2], s[3][r2]));
#pragma unroll
      for (int o = 1; o < 16; o <<= 1) pm = fmaxf(pm, __shfl_xor(pm, o));
      float mn = fmaxf(m[r2], pm);
      float corr = __expf(m[r2] - mn);
      float p0 = __expf(s[0][r2] - mn);
      float p1 = __expf(s[1][r2] - mn);
      float p2 = __expf(s[2][r2] - mn);
      float p3 = __expf(s[3][r2] - mn);
      float ps = p0 + p1 + p2 + p3;
#pragma unroll
      for (int o = 1; o < 16; o <<= 1) ps += __shfl_xor(ps, o);
      lsum[r2] = lsum[r2] * corr + ps;
      m[r2] = mn;
      oacc[0][r2] *= corr; oacc[1][r2] *= corr;
      oacc[2][r2] *= corr; oacc[3][r2] *= corr;
      int prow = (qloc + r2) * 72;
      Ps[prow + rl]      = f2bf(p0);
      Ps[prow + 16 + rl] = f2bf(p1);
      Ps[prow + 32 + rl] = f2bf(p2);
      Ps[prow + 48 + rl] = f2bf(p3);
    }
    bf16x8 pa0 = *(const bf16x8*)&Ps[(w * 16 + rl) * 72 + g * 8];
    bf16x8 pa1 = *(const bf16x8*)&Ps[(w * 16 + rl) * 72 + 32 + g * 8];
    __builtin_amdgcn_s_setprio(1);
#pragma unroll
    for (int nt = 0; nt < 4; ++nt) {
      int r = (nt * 16 + rl) * 64;
      bf16x8 b0 = *(const bf16x8*)&Vs[cur][r + ((0 + g) ^ sw) * 8];
      bf16x8 b1 = *(const bf16x8*)&Vs[cur][r + ((4 + g) ^ sw) * 8];
      oacc[nt] = __builtin_amdgcn_mfma_f32_16x16x32_bf16(pa0, b0, oacc[nt], 0, 0, 0);
      oacc[nt] = __builtin_amdgcn_mfma_f32_16x16x32_bf16(pa1, b1, oacc[nt], 0, 0, 0);
    }
    __builtin_amdgcn_s_setprio(0);
    __syncthreads();
    cur ^= 1;
  }
  int b = bh / NH, h = bh % NH;
  float invl[4];
#pragma unroll
  for (int r2 = 0; r2 < 4; ++r2) invl[r2] = 1.f / lsum[r2];
#pragma unroll
  for (int nt = 0; nt < 4; ++nt) {
    int d = nt * 16 + rl;
#pragma unroll
    for (int r2 = 0; r2 < 4; ++r2) {
      int trow = ti * 64 + qloc + r2;
      yb[((size_t)(b * SEQ + trow)) * DM + h * HD2 + d] = f2bf(oacc[nt][r2] * invl[r2]);
    }
  }
}

// ------- 128x128 GEMM, BK=32, dbuf + COUNTED-vmcnt barriers (T3/T4-min) ------
// modes: 0 bf16 out (+bias); 1 bf16 gelu out (+bias); 3 f32 nontemporal out
__global__ void k_gemm128(const u16* __restrict__ A, const u16* __restrict__ Bt,
                          const float* __restrict__ bias, u16* __restrict__ outb,
                          float* __restrict__ outf, int M, int N, int K, int MT,
                          int mode) {
  __shared__ u16 SM[16384];  // [A0|B0|A1|B1] x4096 u16; alias f32 cw[32][132]
  float* cw = (float*)SM;
  int nwg = gridDim.x;
  int id = blockIdx.x;
  if ((nwg & 7) == 0) id = (id & 7) * (nwg >> 3) + (id >> 3);  // XCD swizzle
  int mt = id % MT, nt = id / MT;
  int m0 = mt * 128, n0 = nt * 128;
  int tid = threadIdx.x;
  int w = tid >> 6, l = tid & 63;
  int srow = w * 16 + (l >> 2);
  int gs = (l & 3) ^ ((l >> 3) & 3);    // pre-swizzled source chunk
  const u16* gA0 = A + (size_t)(m0 + srow) * K + gs * 8;
  const u16* gA1 = A + (size_t)(m0 + 64 + srow) * K + gs * 8;
  int rb0 = n0 + srow;      if (rb0 > N - 1) rb0 = N - 1;
  int rb1 = n0 + 64 + srow; if (rb1 > N - 1) rb1 = N - 1;
  const u16* gB0 = Bt + (size_t)rb0 * K + gs * 8;
  const u16* gB1 = Bt + (size_t)rb1 * K + gs * 8;
  int wm = (w >> 1) * 64, wn = (w & 1) * 64;
  int rl = l & 15, g = l >> 4;
  int sla = g ^ ((rl >> 1) & 3);  // read-side swizzle (lane-constant)
  f32x4 acc[4][4] = {};
  int nK = K >> 5;
  int cur = 0;
  {  // prologue: stage kt=0 into buf0 (full drain once)
    u16* dA = SM + w * 512;
    glds16(gA0, dA); glds16(gA1, dA + 2048);
    u16* dB = SM + 4096 + w * 512;
    glds16(gB0, dB); glds16(gB1, dB + 2048);
  }
  __syncthreads();
  for (int kt = 0; kt < nK; ++kt) {
    if (kt + 1 < nK) {  // issue next-tile stage; stays in flight across barrier
      u16* dA = SM + (cur ^ 1) * 8192 + w * 512;
      glds16(gA0 + (kt + 1) * 32, dA); glds16(gA1 + (kt + 1) * 32, dA + 2048);
      u16* dB = dA + 4096;
      glds16(gB0 + (kt + 1) * 32, dB); glds16(gB1 + (kt + 1) * 32, dB + 2048);
    }
    __builtin_amdgcn_sched_barrier(0);
    if (kt + 1 < nK) asm volatile("s_waitcnt vmcnt(4)" ::: "memory");
    else             asm volatile("s_waitcnt vmcnt(0)" ::: "memory");
    __builtin_amdgcn_s_barrier();
    __builtin_amdgcn_sched_barrier(0);
    const u16* As = SM + cur * 8192;
    const u16* Bs = As + 4096;
    bf16x8 af[4], bfr[4];
    __builtin_amdgcn_s_setprio(1);
#pragma unroll
    for (int i = 0; i < 4; ++i)
      af[i] = *(const bf16x8*)&As[(wm + i * 16 + rl) * 32 + sla * 8];
#pragma unroll
    for (int j = 0; j < 4; ++j)
      bfr[j] = *(const bf16x8*)&Bs[(wn + j * 16 + rl) * 32 + sla * 8];
#pragma unroll
    for (int i = 0; i < 4; ++i)
#pragma unroll
      for (int j = 0; j < 4; ++j)
        acc[i][j] = __builtin_amdgcn_mfma_f32_16x16x32_bf16(af[i], bfr[j],
                                                            acc[i][j], 0, 0, 0);
    __builtin_amdgcn_s_setprio(0);
    __builtin_amdgcn_sched_barrier(0);
    __builtin_amdgcn_s_barrier();   // reads of cur done -> next stage may write
    __builtin_amdgcn_sched_barrier(0);
    cur ^= 1;
  }
  // epilogue: 32-row chunks through LDS
  for (int ch = 0; ch < 4; ++ch) {
    if ((w >> 1) == (ch >> 1)) {
      int ib = (ch & 1) * 2;
#pragma unroll
      for (int ii = 0; ii < 2; ++ii) {
#pragma unroll
        for (int j = 0; j < 4; ++j) {
          int col = wn + j * 16 + rl;
#pragma unroll
          for (int r2 = 0; r2 < 4; ++r2) {
            int rowc = ii * 16 + g * 4 + r2;
            float v = acc[ib + ii][j][r2];
            if (mode != 3) {
              v += bias[n0 + col];
              if (mode == 1) {
                float u = 0.7978845608028654f * (v + 0.044715f * v * v * v);
                v = 0.5f * v * (1.f + tanhf(u));
              }
            }
            cw[rowc * 132 + col] = v;
          }
        }
      }
    }
    __syncthreads();
    if (mode == 3) {
      for (int t = tid; t < 4096; t += 256) {
        int rowc = t >> 7, col = t & 127;
        int gc = n0 + col;
        if (gc < N)
          __builtin_nontemporal_store(cw[rowc * 132 + col],
                                      &outf[(size_t)(m0 + ch * 32 + rowc) * N + gc]);
      }
    } else {  // bf16 packed u32 writes (N multiple of 128)
      for (int t = tid; t < 2048; t += 256) {
        int rowc = t >> 6, cp = t & 63;
        u32 wv = (u32)f2bf(cw[rowc * 132 + 2 * cp]) |
                 ((u32)f2bf(cw[rowc * 132 + 2 * cp + 1]) << 16);
        *(u32*)&outb[(size_t)(m0 + ch * 32 + rowc) * N + n0 + 2 * cp] = wv;
      }
    }
    __syncthreads();
  }
}

// ------- 64x64-tile GEMM, BK=64, dbuf + counted vmcnt, split-K ---------------
// modes: 0 bf16 out; 1 bf16 gelu out; 2 f32 atomic residual add (+bias at sk0)
__global__ void k_gemm64(const u16* __restrict__ A, const u16* __restrict__ Bt,
                         const float* __restrict__ bias, u16* __restrict__ outb,
                         float* __restrict__ outf, int M, int N, int K, int MT,
                         int mode) {
  __shared__ u16 As[8192];  // 2 x [64][64]
  __shared__ u16 Bs[8192];
  int nwg = gridDim.x;
  int id = blockIdx.x;
  if ((nwg & 7) == 0) id = (id & 7) * (nwg >> 3) + (id >> 3);  // XCD swizzle
  int mt = id % MT, nt = id / MT;
  int sk = blockIdx.y, nsk = gridDim.y;
  int Kc = K / nsk, k0 = sk * Kc;
  int m0 = mt * 64, n0 = nt * 64;
  int tid = threadIdx.x;
  int w = tid >> 6, l = tid & 63;
  int row0 = tid >> 3, slot0 = tid & 7;
  int gs0 = slot0 ^ (row0 & 7);
  const u16* gA0 = A + (size_t)(m0 + row0) * K + k0 + gs0 * 8;
  const u16* gA1 = gA0 + (size_t)32 * K;
  const u16* gB0 = Bt + (size_t)(n0 + row0) * K + k0 + gs0 * 8;
  const u16* gB1 = gB0 + (size_t)32 * K;
  int wm = (w >> 1) * 32, wn = (w & 1) * 32;
  int rl = l & 15, g = l >> 4;
  int sl0 = g ^ (rl & 7), sl1 = (4 + g) ^ (rl & 7);
  f32x4 acc[2][2] = {};
  int nK = Kc >> 6;
  int cur = 0;
  {  // prologue stage kt=0 -> buf0
    glds16(gA0, As + w * 512); glds16(gA1, As + 2048 + w * 512);
    glds16(gB0, Bs + w * 512); glds16(gB1, Bs + 2048 + w * 512);
  }
  __syncthreads();
  for (int kt = 0; kt < nK; ++kt) {
    if (kt + 1 < nK) {
      int nx = (cur ^ 1) * 4096;
      glds16(gA0 + (kt + 1) * 64, As + nx + w * 512);
      glds16(gA1 + (kt + 1) * 64, As + nx + 2048 + w * 512);
      glds16(gB0 + (kt + 1) * 64, Bs + nx + w * 512);
      glds16(gB1 + (kt + 1) * 64, Bs + nx + 2048 + w * 512);
    }
    __builtin_amdgcn_sched_barrier(0);
    if (kt + 1 < nK) asm volatile("s_waitcnt vmcnt(4)" ::: "memory");
    else             asm volatile("s_waitcnt vmcnt(0)" ::: "memory");
    __builtin_amdgcn_s_barrier();
    __builtin_amdgcn_sched_barrier(0);
    const u16* Ac = As + cur * 4096;
    const u16* Bc = Bs + cur * 4096;
    bf16x8 a0[2], a1[2], b0[2], b1[2];
    __builtin_amdgcn_s_setprio(1);
#pragma unroll
    for (int i = 0; i < 2; ++i) {
      int r = (wm + i * 16 + rl) * 64;
      a0[i] = *(const bf16x8*)&Ac[r + sl0 * 8];
      a1[i] = *(const bf16x8*)&Ac[r + sl1 * 8];
    }
#pragma unroll
    for (int j = 0; j < 2; ++j) {
      int r = (wn + j * 16 + rl) * 64;
      b0[j] = *(const bf16x8*)&Bc[r + sl0 * 8];
      b1[j] = *(const bf16x8*)&Bc[r + sl1 * 8];
    }
#pragma unroll
    for (int i = 0; i < 2; ++i)
#pragma unroll
      for (int j = 0; j < 2; ++j) {
        acc[i][j] = __builtin_amdgcn_mfma_f32_16x16x32_bf16(a0[i], b0[j],
                                                            acc[i][j], 0, 0, 0);
        acc[i][j] = __builtin_amdgcn_mfma_f32_16x16x32_bf16(a1[i], b1[j],
                                                            acc[i][j], 0, 0, 0);
      }
    __builtin_amdgcn_s_setprio(0);
    __builtin_amdgcn_sched_barrier(0);
    __builtin_amdgcn_s_barrier();
    __builtin_amdgcn_sched_barrier(0);
    cur ^= 1;
  }
#pragma unroll
  for (int i = 0; i < 2; ++i) {
#pragma unroll
    for (int j = 0; j < 2; ++j) {
      int col = n0 + wn + j * 16 + rl;
      float bv = bias ? bias[col] : 0.f;
#pragma unroll
      for (int r2 = 0; r2 < 4; ++r2) {
        int row = m0 + wm + i * 16 + g * 4 + r2;
        size_t oi = (size_t)row * N + col;
        float v = acc[i][j][r2];
        if (mode == 0) {
          outb[oi] = f2bf(v + bv);
        } else if (mode == 1) {
          v += bv;
          float u = 0.7978845608028654f * (v + 0.044715f * v * v * v);
          outb[oi] = f2bf(0.5f * v * (1.f + tanhf(u)));
        } else {
          if (sk == 0) v += bv;
          atomicAdd(&outf[oi], v);
        }
      }
    }
  }
}

// ---------------- fallback GEMM (f32 B, on-the-fly cvt) — logits only --------
__global__ void k_gemm_f32b(const u16* __restrict__ A, const float* __restrict__ B,
                            float* __restrict__ outf, int M, int N, int K) {
  __shared__ u16 As[128 * 40];
  __shared__ u16 Bs[4 * 128 * 12];
  int tid = threadIdx.x;
  int wid = tid >> 6, lane = tid & 63;
  int rl = lane & 15, g = lane >> 4;
  int m0 = blockIdx.x * 128, n0 = blockIdx.y * 128;
  int wm = (wid >> 1) * 64, wn = (wid & 1) * 64;
  int ar = tid >> 2, ac = tid & 3;
  int bn = tid & 127, bq = tid >> 7;
  f32x4 acc[4][4] = {};
  int nK = K / 32;
  for (int kt = 0; kt < nK; ++kt) {
    __syncthreads();
    {
      const u16* ga = A + (size_t)(m0 + ar) * K + kt * 32 + ac * 8;
      *(uint4*)&As[ar * 40 + ac * 8] = *(const uint4*)ga;
      *(uint4*)&As[(ar + 64) * 40 + ac * 8] = *(const uint4*)(ga + (size_t)64 * K);
    }
    int col = n0 + bn;
#pragma unroll
    for (int r = 0; r < 4; ++r) {
      int kq = bq + 2 * r;
      int kk = kt * 32 + kq * 4;
      float f0 = 0.f, f1 = 0.f, f2v = 0.f, f3 = 0.f;
      if (col < N) {
        const float* gb = B + (size_t)kk * N + col;
        f0 = gb[0]; f1 = gb[(size_t)N]; f2v = gb[(size_t)2 * N]; f3 = gb[(size_t)3 * N];
      }
      uint2 wv;
      wv.x = (u32)f2bf(f0) | ((u32)f2bf(f1) << 16);
      wv.y = (u32)f2bf(f2v) | ((u32)f2bf(f3) << 16);
      *(uint2*)&Bs[(kq >> 1) * 1536 + bn * 12 + (kq & 1) * 4] = wv;
    }
    __syncthreads();
    bf16x8 af[4], bfr[4];
#pragma unroll
    for (int mt = 0; mt < 4; ++mt)
      af[mt] = *(const bf16x8*)&As[(wm + mt * 16 + rl) * 40 + g * 8];
#pragma unroll
    for (int nt = 0; nt < 4; ++nt) {
      const u16* p = &Bs[g * 1536 + (wn + nt * 16 + rl) * 12];
      union { bf16x8 v; uint2 u2[2]; } tmp;
      tmp.u2[0] = *(const uint2*)p;
      tmp.u2[1] = *(const uint2*)(p + 4);
      bfr[nt] = tmp.v;
    }
#pragma unroll
    for (int mt = 0; mt < 4; ++mt)
#pragma unroll
      for (int nt = 0; nt < 4; ++nt)
        acc[mt][nt] = __builtin_amdgcn_mfma_f32_16x16x32_bf16(af[mt], bfr[nt],
                                                              acc[mt][nt], 0, 0, 0);
  }
#pragma unroll
  for (int mt = 0; mt < 4; ++mt)
#pragma unroll
    for (int nt = 0; nt < 4; ++nt) {
      int col = n0 + wn + nt * 16 + rl;
      if (col >= N) continue;
#pragma unroll
      for (int r2 = 0; r2 < 4; ++r2) {
        int row = m0 + wm + mt * 16 + g * 4 + r2;
        outf[(size_t)row * N + col] = acc[mt][nt][r2];
      }
    }
}

extern "C" void kernel_launch(void* const* d_in, const int* in_sizes, int n_in,
                              void* d_out, int out_size, void* d_ws, size_t ws_size,
                              hipStream_t stream) {
  (void)in_sizes; (void)n_in; (void)out_size;
  const int*   idx  = (const int*)  d_in[0];
  const float* wte  = (const float*)d_in[1];
  const float* ln1g = (const float*)d_in[2];
  const float* ln1b = (const float*)d_in[3];
  const float* Wqkv = (const float*)d_in[4];
  const float* bqkv = (const float*)d_in[5];
  const float* Wo   = (const float*)d_in[6];
  const float* bo   = (const float*)d_in[7];
  const float* ln2g = (const float*)d_in[8];
  const float* ln2b = (const float*)d_in[9];
  const float* Wfc  = (const float*)d_in[10];
  const float* bfc  = (const float*)d_in[11];
  const float* Wp   = (const float*)d_in[12];
  const float* bp   = (const float*)d_in[13];
  const float* lnfg = (const float*)d_in[14];
  const float* lnfb = (const float*)d_in[15];
  const float* Wlm  = (const float*)d_in[16];
  float* out = (float*)d_out;

  // Scratch packed into d_out (all dead before the logits GEMM rewrites d_out).
  char* sb = (char*)d_out;
  size_t off = 0;
  auto alloc = [&](size_t bytes) {
    char* p = sb + off;
    off += (bytes + 255) & ~(size_t)255;
    return (void*)p;
  };
  float* xf  = (float*)alloc((size_t)BT * DM * 4);
  u16* h1b   = (u16*)alloc((size_t)BT * DM * 2);
  u16* h2b   = (u16*)alloc((size_t)BT * DM * 2);
  u16* qkvb  = (u16*)alloc((size_t)BT * 3 * DM * 2);
  u16* qr    = (u16*)alloc((size_t)BT * DM * 2);
  u16* kr    = (u16*)alloc((size_t)BT * DM * 2);
  u16* vT    = (u16*)alloc((size_t)BT * DM * 2);
  u16* yb    = (u16*)alloc((size_t)BT * DM * 2);
  u16* hgel  = (u16*)alloc((size_t)BT * 4 * DM * 2);
  // transposed bf16 weights (also dead before logits GEMM)
  u16* wqkvT = (u16*)alloc((size_t)NLAYER * 3 * DM * DM * 2);
  u16* woT   = (u16*)alloc((size_t)NLAYER * DM * DM * 2);
  u16* wfcT  = (u16*)alloc((size_t)NLAYER * 4 * DM * DM * 2);
  u16* wpT   = (u16*)alloc((size_t)NLAYER * 4 * DM * DM * 2);

  // Wlm^T (77 MB) must survive the logits GEMM -> d_ws if it fits.
  size_t wlmT_bytes = (size_t)NVOCAB * DM * 2;
  size_t xlnf_bytes = (size_t)BT * DM * 2;
  bool fast_lm = ws_size >= wlmT_bytes + xlnf_bytes + 512;
  u16* wlmT = (u16*)d_ws;
  u16* xlnf = fast_lm ? (u16*)((char*)d_ws + ((wlmT_bytes + 255) & ~(size_t)255))
                      : (u16*)d_ws;

  // ---- weight conversion pass (64x64 tiles) ----
  for (int l = 0; l < NLAYER; ++l) {
    k_cvtT<<<dim3((3 * DM + 63) / 64, DM / 64), 256, 0, stream>>>(
        Wqkv + (size_t)l * DM * 3 * DM, wqkvT + (size_t)l * 3 * DM * DM, DM, 3 * DM);
    k_cvtT<<<dim3(DM / 64, DM / 64), 256, 0, stream>>>(
        Wo + (size_t)l * DM * DM, woT + (size_t)l * DM * DM, DM, DM);
    k_cvtT<<<dim3((4 * DM) / 64, DM / 64), 256, 0, stream>>>(
        Wfc + (size_t)l * DM * 4 * DM, wfcT + (size_t)l * 4 * DM * DM, DM, 4 * DM);
    k_cvtT<<<dim3(DM / 64, (4 * DM) / 64), 256, 0, stream>>>(
        Wp + (size_t)l * 4 * DM * DM, wpT + (size_t)l * 4 * DM * DM, 4 * DM, DM);
  }
  if (fast_lm)
    k_cvtT<<<dim3((NVOCAB + 63) / 64, DM / 64), 256, 0, stream>>>(Wlm, wlmT, DM, NVOCAB);

  k_embed<<<BT, 256, 0, stream>>>(idx, wte, xf);
  for (int l = 0; l < NLAYER; ++l) {
    k_ln<<<BT, 256, 0, stream>>>(xf, ln1g + l * DM, ln1b + l * DM,
                                 ln2g + l * DM, ln2b + l * DM, h1b, h2b);
    k_gemm128<<<(BT / 128) * (3 * DM / 128), 256, 0, stream>>>(
        h1b, wqkvT + (size_t)l * 3 * DM * DM, bqkv + (size_t)l * 3 * DM,
        qkvb, nullptr, BT, 3 * DM, DM, BT / 128, 0);
    k_rope<<<(2 * SEQ * NH * 32) / 256, 256, 0, stream>>>(qkvb, qr, kr);
    k_vtrans<<<dim3(SEQ / 64, 2 * NH), 256, 0, stream>>>(qkvb, vT);
    k_attn<<<dim3(SEQ / 64, 2 * NH), 256, 0, stream>>>(qr, kr, vT, yb);
    k_gemm64<<<dim3((BT / 64) * (DM / 64), 2), 256, 0, stream>>>(
        yb, woT + (size_t)l * DM * DM, bo + (size_t)l * DM,
        nullptr, xf, BT, DM, DM, BT / 64, 2);
    k_gemm128<<<(BT / 128) * (4 * DM / 128), 256, 0, stream>>>(
        h2b, wfcT + (size_t)l * 4 * DM * DM, bfc + (size_t)l * 4 * DM,
        hgel, nullptr, BT, 4 * DM, DM, BT / 128, 1);
    k_gemm64<<<dim3((BT / 64) * (DM / 64), 4), 256, 0, stream>>>(
        hgel, wpT + (size_t)l * 4 * DM * DM, bp + (size_t)l * DM,
        nullptr, xf, BT, DM, 4 * DM, BT / 64, 2);
  }
  k_ln<<<BT, 256, 0, stream>>>(xf, lnfg, lnfb, nullptr, nullptr, xlnf, nullptr);
  if (fast_lm) {
    int nt = (NVOCAB + 127) / 128;
    k_gemm128<<<(BT / 128) * nt, 256, 0, stream>>>(
        xlnf, wlmT, nullptr, nullptr, out, BT, NVOCAB, DM, BT / 128, 3);
  } else {
    k_gemm_f32b<<<dim3(BT / 128, (NVOCAB + 127) / 128), 256, 0, stream>>>(
        xlnf, Wlm, out, BT, NVOCAB, DM);
  }
}

// Round 7
// 978.311 us; speedup vs baseline: 1.6081x; 1.6081x over previous
//
#include <hip/hip_runtime.h>

typedef unsigned short u16;
typedef unsigned int u32;
typedef __attribute__((ext_vector_type(8))) short bf16x8;
typedef __attribute__((ext_vector_type(4))) float f32x4;

#define SEQ 1024
#define DM 768
#define NH 12
#define HD2 64
#define NLAYER 4
#define NVOCAB 50257
#define BT 2048  // B*T

__device__ __forceinline__ u16 f2bf(float f) {
  union { float f; u32 u; } v; v.f = f;
  u32 r = v.u + 0x7FFFu + ((v.u >> 16) & 1u);
  return (u16)(r >> 16);
}
__device__ __forceinline__ float bf2f(u16 u) {
  union { u32 u; float f; } v; v.u = ((u32)u) << 16;
  return v.f;
}

__device__ __forceinline__ void glds16(const u16* g, u16* l) {
  __builtin_amdgcn_global_load_lds(
      (const __attribute__((address_space(1))) u32*)(const void*)g,
      (__attribute__((address_space(3))) u32*)(void*)l, 16, 0, 0);
}

// ---------------- embedding ----------------
__global__ void k_embed(const int* __restrict__ idx, const float* __restrict__ wte,
                        float* __restrict__ xf) {
  int r = blockIdx.x;
  int tok = idx[r];
  const float* s = wte + (size_t)tok * DM;
  float* d = xf + (size_t)r * DM;
  for (int c = threadIdx.x; c < DM; c += 256) d[c] = s[c];
}

// ---------------- rope trig tables: [SEQ][16] cos/sin ----------------
__global__ void k_trig(float* __restrict__ ctab, float* __restrict__ stab) {
  int gid = blockIdx.x * 256 + threadIdx.x;  // over SEQ*16
  int tt = gid >> 4, j = gid & 15;
  float inv = powf(10000.f, -(float)j * (1.f / 32.f));
  float ang = (float)tt * inv;
  ctab[gid] = cosf(ang);
  stab[gid] = sinf(ang);
}

// ------- transpose + f32->bf16: in[R,C] f32 -> out[C,R] bf16 (64x64 tile) ----
__global__ void k_cvtT(const float* __restrict__ in, u16* __restrict__ out,
                       int R, int C) {
  __shared__ u16 t[64][68];
  int c0 = blockIdx.x * 64, r0 = blockIdx.y * 64;  // R always multiple of 64
  int tx = threadIdx.x & 15, ty = threadIdx.x >> 4;
  int c = c0 + tx * 4;
#pragma unroll
  for (int i = 0; i < 4; ++i) {
    int r = r0 + ty + i * 16;
    float4 v = make_float4(0.f, 0.f, 0.f, 0.f);
    if (c + 3 < C) {
      v = *(const float4*)&in[(size_t)r * C + c];
    } else {
      if (c + 0 < C) v.x = in[(size_t)r * C + c];
      if (c + 1 < C) v.y = in[(size_t)r * C + c + 1];
      if (c + 2 < C) v.z = in[(size_t)r * C + c + 2];
      if (c + 3 < C) v.w = in[(size_t)r * C + c + 3];
    }
    t[ty + i * 16][tx * 4 + 0] = f2bf(v.x);
    t[ty + i * 16][tx * 4 + 1] = f2bf(v.y);
    t[ty + i * 16][tx * 4 + 2] = f2bf(v.z);
    t[ty + i * 16][tx * 4 + 3] = f2bf(v.w);
  }
  __syncthreads();
  int wl = threadIdx.x & 31, grp = threadIdx.x >> 5;
#pragma unroll
  for (int it = 0; it < 8; ++it) {
    int cc = it * 8 + grp;
    int gcol = c0 + cc;
    if (gcol < C) {
      u32 wv = (u32)t[2 * wl][cc] | ((u32)t[2 * wl + 1][cc] << 16);
      *(u32*)&out[(size_t)gcol * R + r0 + 2 * wl] = wv;
    }
  }
}

// ---------------- block reductions (256 thr = 4 waves) ----------------
__device__ __forceinline__ float bsum(float v, float* red) {
#pragma unroll
  for (int o = 32; o > 0; o >>= 1) v += __shfl_down(v, o);
  if ((threadIdx.x & 63) == 0) red[threadIdx.x >> 6] = v;
  __syncthreads();
  if (threadIdx.x == 0) red[4] = red[0] + red[1] + red[2] + red[3];
  __syncthreads();
  return red[4];
}

// ---------------- dual layernorm (both read same x) ----------------
__global__ void k_ln(const float* __restrict__ x, const float* __restrict__ g1,
                     const float* __restrict__ b1, const float* __restrict__ g2,
                     const float* __restrict__ b2, u16* __restrict__ o1,
                     u16* __restrict__ o2) {
  __shared__ float red[8];
  int r = blockIdx.x;
  int t = threadIdx.x;
  const float* xr = x + (size_t)r * DM;
  float v0 = xr[t], v1 = xr[t + 256], v2 = xr[t + 512];
  float mean = bsum(v0 + v1 + v2, red) * (1.f / DM);
  float d0 = v0 - mean, d1 = v1 - mean, d2 = v2 - mean;
  float var = bsum(d0 * d0 + d1 * d1 + d2 * d2, red) * (1.f / DM);
  float rstd = rsqrtf(var + 1e-5f);
  u16* p1 = o1 + (size_t)r * DM;
  p1[t]       = f2bf(d0 * rstd * g1[t]       + b1[t]);
  p1[t + 256] = f2bf(d1 * rstd * g1[t + 256] + b1[t + 256]);
  p1[t + 512] = f2bf(d2 * rstd * g1[t + 512] + b1[t + 512]);
  if (o2) {
    u16* p2 = o2 + (size_t)r * DM;
    p2[t]       = f2bf(d0 * rstd * g2[t]       + b2[t]);
    p2[t + 256] = f2bf(d1 * rstd * g2[t + 256] + b2[t + 256]);
    p2[t + 512] = f2bf(d2 * rstd * g2[t + 512] + b2[t + 512]);
  }
}

// ---------------- fused flash attention, glds-staged double-buffered K/V ----
__global__ void k_attn(const u16* __restrict__ qr, const u16* __restrict__ kr,
                       const u16* __restrict__ vT, u16* __restrict__ yb) {
  int ti = (int)gridDim.x - 1 - (int)blockIdx.x;  // big tiles first
  int bh = blockIdx.y;
  __shared__ u16 Ps[64 * 72];       // Q staging, then P tile (wave-private rows)
  __shared__ u16 Ks[2][4096];       // [64][64] XOR-swizzled
  __shared__ u16 Vs[2][4096];
  int tid = threadIdx.x;
  int rr = tid >> 2, cc = tid & 3;
  int w = tid >> 6, l = tid & 63;
  int rl = l & 15, g = l >> 4;
  {
    const u16* gq = qr + ((size_t)bh * SEQ + ti * 64 + rr) * HD2;
    *(uint4*)&Ps[rr * 72 + cc * 8]      = *(const uint4*)(gq + cc * 8);
    *(uint4*)&Ps[rr * 72 + cc * 8 + 32] = *(const uint4*)(gq + cc * 8 + 32);
  }
  int srow = w * 8 + (l >> 3);
  int gs = (l & 7) ^ (l >> 3);
  const u16* gkb = kr + (size_t)bh * SEQ * HD2;
  const u16* gvb = vT + (size_t)bh * HD2 * SEQ;
  glds16(gkb + (size_t)srow * 64 + gs * 8,        &Ks[0][w * 512]);
  glds16(gkb + (size_t)(32 + srow) * 64 + gs * 8, &Ks[0][2048 + w * 512]);
  glds16(gvb + (size_t)srow * SEQ + gs * 8,       &Vs[0][w * 512]);
  glds16(gvb + (size_t)(32 + srow) * SEQ + gs * 8,&Vs[0][2048 + w * 512]);
  __syncthreads();
  bf16x8 aq0 = *(const bf16x8*)&Ps[(w * 16 + rl) * 72 + g * 8];
  bf16x8 aq1 = *(const bf16x8*)&Ps[(w * 16 + rl) * 72 + 32 + g * 8];
  float m[4], lsum[4];
  f32x4 oacc[4] = {};
#pragma unroll
  for (int r2 = 0; r2 < 4; ++r2) { m[r2] = -3.0e38f; lsum[r2] = 0.f; }
  int qloc = w * 16 + g * 4;
  int sw = rl & 7;
  int cur = 0;
  for (int kt = 0; kt <= ti; ++kt) {
    if (kt < ti) {
      int nx = cur ^ 1;
      glds16(gkb + (size_t)((kt + 1) * 64 + srow) * 64 + gs * 8,      &Ks[nx][w * 512]);
      glds16(gkb + (size_t)((kt + 1) * 64 + 32 + srow) * 64 + gs * 8, &Ks[nx][2048 + w * 512]);
      glds16(gvb + (size_t)srow * SEQ + (kt + 1) * 64 + gs * 8,       &Vs[nx][w * 512]);
      glds16(gvb + (size_t)(32 + srow) * SEQ + (kt + 1) * 64 + gs * 8,&Vs[nx][2048 + w * 512]);
    }
    f32x4 s[4] = {};
    __builtin_amdgcn_s_setprio(1);
#pragma unroll
    for (int nt = 0; nt < 4; ++nt) {
      int r = (nt * 16 + rl) * 64;
      bf16x8 b0 = *(const bf16x8*)&Ks[cur][r + ((0 + g) ^ sw) * 8];
      bf16x8 b1 = *(const bf16x8*)&Ks[cur][r + ((4 + g) ^ sw) * 8];
      s[nt] = __builtin_amdgcn_mfma_f32_16x16x32_bf16(aq0, b0, s[nt], 0, 0, 0);
      s[nt] = __builtin_amdgcn_mfma_f32_16x16x32_bf16(aq1, b1, s[nt], 0, 0, 0);
    }
    __builtin_amdgcn_s_setprio(0);
#pragma unroll
    for (int nt = 0; nt < 4; ++nt) s[nt] *= 0.125f;
    if (kt == ti) {
#pragma unroll
      for (int nt = 0; nt < 4; ++nt) {
        int col = nt * 16 + rl;
#pragma unroll
        for (int r2 = 0; r2 < 4; ++r2)
          if (col > qloc + r2) s[nt][r2] = -3.0e38f;
      }
    }
#pragma unroll
    for (int r2 = 0; r2 < 4; ++r2) {
      float pm = fmaxf(fmaxf(s[0][r2], s[1][r2]), fmaxf(s[2][r2], s[3][r2]));
#pragma unroll
      for (int o = 1; o < 16; o <<= 1) pm = fmaxf(pm, __shfl_xor(pm, o));
      float mn = fmaxf(m[r2], pm);
      float corr = __expf(m[r2] - mn);
      float p0 = __expf(s[0][r2] - mn);
      float p1 = __expf(s[1][r2] - mn);
      float p2 = __expf(s[2][r2] - mn);
      float p3 = __expf(s[3][r2] - mn);
      float ps = p0 + p1 + p2 + p3;
#pragma unroll
      for (int o = 1; o < 16; o <<= 1) ps += __shfl_xor(ps, o);
      lsum[r2] = lsum[r2] * corr + ps;
      m[r2] = mn;
      oacc[0][r2] *= corr; oacc[1][r2] *= corr;
      oacc[2][r2] *= corr; oacc[3][r2] *= corr;
      int prow = (qloc + r2) * 72;
      Ps[prow + rl]      = f2bf(p0);
      Ps[prow + 16 + rl] = f2bf(p1);
      Ps[prow + 32 + rl] = f2bf(p2);
      Ps[prow + 48 + rl] = f2bf(p3);
    }
    bf16x8 pa0 = *(const bf16x8*)&Ps[(w * 16 + rl) * 72 + g * 8];
    bf16x8 pa1 = *(const bf16x8*)&Ps[(w * 16 + rl) * 72 + 32 + g * 8];
    __builtin_amdgcn_s_setprio(1);
#pragma unroll
    for (int nt = 0; nt < 4; ++nt) {
      int r = (nt * 16 + rl) * 64;
      bf16x8 b0 = *(const bf16x8*)&Vs[cur][r + ((0 + g) ^ sw) * 8];
      bf16x8 b1 = *(const bf16x8*)&Vs[cur][r + ((4 + g) ^ sw) * 8];
      oacc[nt] = __builtin_amdgcn_mfma_f32_16x16x32_bf16(pa0, b0, oacc[nt], 0, 0, 0);
      oacc[nt] = __builtin_amdgcn_mfma_f32_16x16x32_bf16(pa1, b1, oacc[nt], 0, 0, 0);
    }
    __builtin_amdgcn_s_setprio(0);
    __syncthreads();
    cur ^= 1;
  }
  int b = bh / NH, h = bh % NH;
  float invl[4];
#pragma unroll
  for (int r2 = 0; r2 < 4; ++r2) invl[r2] = 1.f / lsum[r2];
#pragma unroll
  for (int nt = 0; nt < 4; ++nt) {
    int d = nt * 16 + rl;
#pragma unroll
    for (int r2 = 0; r2 < 4; ++r2) {
      int trow = ti * 64 + qloc + r2;
      yb[((size_t)(b * SEQ + trow)) * DM + h * HD2 + d] = f2bf(oacc[nt][r2] * invl[r2]);
    }
  }
}

// ---------------- logits GEMM: C[M,N]f32 = A[M,K]bf16 * Bt[N,K]bf16 ---------
// 128x128 tile, BK=32, dbuf single-__syncthreads loop (round-5 proven),
// source-preswizzled LDS, LDS-staged coalesced nontemporal f32 epilogue.
__global__ void k_logits(const u16* __restrict__ A, const u16* __restrict__ Bt,
                         float* __restrict__ outf, int M, int N, int K, int MT) {
  __shared__ u16 SM[16384];  // [As0|Bs0|As1|Bs1] 4096 u16 each; alias cw[32][132]
  float* cw = (float*)SM;
  int nwg = gridDim.x;
  int id = blockIdx.x;
  if ((nwg & 7) == 0) id = (id & 7) * (nwg >> 3) + (id >> 3);  // XCD swizzle
  int mt = id % MT, nt = id / MT;
  int m0 = mt * 128, n0 = nt * 128;
  int tid = threadIdx.x;
  int w = tid >> 6, l = tid & 63;
  int srow = w * 16 + (l >> 2);
  int gs = (l & 3) ^ ((l >> 3) & 3);    // pre-swizzled source chunk
  const u16* gA0 = A + (size_t)(m0 + srow) * K + gs * 8;
  const u16* gA1 = A + (size_t)(m0 + 64 + srow) * K + gs * 8;
  int rb0 = n0 + srow;      if (rb0 > N - 1) rb0 = N - 1;
  int rb1 = n0 + 64 + srow; if (rb1 > N - 1) rb1 = N - 1;
  const u16* gB0 = Bt + (size_t)rb0 * K + gs * 8;
  const u16* gB1 = Bt + (size_t)rb1 * K + gs * 8;
  int wm = (w >> 1) * 64, wn = (w & 1) * 64;
  int rl = l & 15, g = l >> 4;
  int sla = g ^ ((rl >> 1) & 3);  // read-side swizzle (lane-constant)
  f32x4 acc[4][4] = {};
  int nK = K >> 5;
  int cur = 0;
  {  // prologue: stage kt=0 into buf0
    u16* dA = SM + w * 512;
    glds16(gA0, dA); glds16(gA1, dA + 2048);
    u16* dB = SM + 4096 + w * 512;
    glds16(gB0, dB); glds16(gB1, dB + 2048);
  }
  __syncthreads();
  for (int kt = 0; kt < nK; ++kt) {
    if (kt + 1 < nK) {  // issue next-tile stage before compute
      u16* dA = SM + (cur ^ 1) * 8192 + w * 512;
      glds16(gA0 + (kt + 1) * 32, dA); glds16(gA1 + (kt + 1) * 32, dA + 2048);
      u16* dB = dA + 4096;
      glds16(gB0 + (kt + 1) * 32, dB); glds16(gB1 + (kt + 1) * 32, dB + 2048);
    }
    const u16* As = SM + cur * 8192;
    const u16* Bs = As + 4096;
    bf16x8 af[4], bfr[4];
    __builtin_amdgcn_s_setprio(1);
#pragma unroll
    for (int i = 0; i < 4; ++i)
      af[i] = *(const bf16x8*)&As[(wm + i * 16 + rl) * 32 + sla * 8];
#pragma unroll
    for (int j = 0; j < 4; ++j)
      bfr[j] = *(const bf16x8*)&Bs[(wn + j * 16 + rl) * 32 + sla * 8];
#pragma unroll
    for (int i = 0; i < 4; ++i)
#pragma unroll
      for (int j = 0; j < 4; ++j)
        acc[i][j] = __builtin_amdgcn_mfma_f32_16x16x32_bf16(af[i], bfr[j],
                                                            acc[i][j], 0, 0, 0);
    __builtin_amdgcn_s_setprio(0);
    __syncthreads();
    cur ^= 1;
  }
  // epilogue: 32-row chunks through LDS, coalesced nontemporal f32 row writes
  for (int ch = 0; ch < 4; ++ch) {
    if ((w >> 1) == (ch >> 1)) {
      int ib = (ch & 1) * 2;
#pragma unroll
      for (int ii = 0; ii < 2; ++ii) {
#pragma unroll
        for (int j = 0; j < 4; ++j) {
          int col = wn + j * 16 + rl;
#pragma unroll
          for (int r2 = 0; r2 < 4; ++r2) {
            int rowc = ii * 16 + g * 4 + r2;
            cw[rowc * 132 + col] = acc[ib + ii][j][r2];
          }
        }
      }
    }
    __syncthreads();
    for (int t = tid; t < 4096; t += 256) {
      int rowc = t >> 7, col = t & 127;
      int gc = n0 + col;
      if (gc < N)
        __builtin_nontemporal_store(cw[rowc * 132 + col],
                                    &outf[(size_t)(m0 + ch * 32 + rowc) * N + gc]);
    }
    __syncthreads();
  }
}

// ------- 64x64-tile GEMM, BK=64, dbuf (round-5 loop), split-K ---------------
// modes: 0 bf16 out; 1 bf16 gelu out; 2 f32 atomic residual add (+bias at sk0)
//        4 fused qkv: rope(q,k) -> qr/kr [bh][t][d]; v -> vT [bh][d][t]
__global__ void k_gemm64(const u16* __restrict__ A, const u16* __restrict__ Bt,
                         const float* __restrict__ bias, u16* __restrict__ outb,
                         float* __restrict__ outf, int M, int N, int K, int MT,
                         int mode, const float* __restrict__ ctab,
                         const float* __restrict__ stab, u16* __restrict__ qrp,
                         u16* __restrict__ krp, u16* __restrict__ vTp) {
  __shared__ u16 SM2[16384];  // As | Bs (2x dbuf); alias f32 cw[64][68] for mode 4
  u16* As = SM2;
  u16* Bs = SM2 + 8192;
  float* cw = (float*)SM2;
  int nwg = gridDim.x;
  int id = blockIdx.x;
  if ((nwg & 7) == 0) id = (id & 7) * (nwg >> 3) + (id >> 3);  // XCD swizzle
  int mt = id % MT, nt = id / MT;
  int sk = blockIdx.y, nsk = gridDim.y;
  int Kc = K / nsk, k0 = sk * Kc;
  int m0 = mt * 64, n0 = nt * 64;
  int tid = threadIdx.x;
  int w = tid >> 6, l = tid & 63;
  int row0 = tid >> 3, slot0 = tid & 7;
  int gs0 = slot0 ^ (row0 & 7);
  const u16* gA0 = A + (size_t)(m0 + row0) * K + k0 + gs0 * 8;
  const u16* gA1 = gA0 + (size_t)32 * K;
  const u16* gB0 = Bt + (size_t)(n0 + row0) * K + k0 + gs0 * 8;
  const u16* gB1 = gB0 + (size_t)32 * K;
  int wm = (w >> 1) * 32, wn = (w & 1) * 32;
  int rl = l & 15, g = l >> 4;
  int sl0 = g ^ (rl & 7), sl1 = (4 + g) ^ (rl & 7);
  f32x4 acc[2][2] = {};
  int nK = Kc >> 6;
  int cur = 0;
  {  // prologue stage kt=0 -> buf0
    glds16(gA0, As + w * 512); glds16(gA1, As + 2048 + w * 512);
    glds16(gB0, Bs + w * 512); glds16(gB1, Bs + 2048 + w * 512);
  }
  __syncthreads();
  for (int kt = 0; kt < nK; ++kt) {
    if (kt + 1 < nK) {
      int nx = (cur ^ 1) * 4096;
      glds16(gA0 + (kt + 1) * 64, As + nx + w * 512);
      glds16(gA1 + (kt + 1) * 64, As + nx + 2048 + w * 512);
      glds16(gB0 + (kt + 1) * 64, Bs + nx + w * 512);
      glds16(gB1 + (kt + 1) * 64, Bs + nx + 2048 + w * 512);
    }
    const u16* Ac = As + cur * 4096;
    const u16* Bc = Bs + cur * 4096;
    bf16x8 a0[2], a1[2], b0[2], b1[2];
    __builtin_amdgcn_s_setprio(1);
#pragma unroll
    for (int i = 0; i < 2; ++i) {
      int r = (wm + i * 16 + rl) * 64;
      a0[i] = *(const bf16x8*)&Ac[r + sl0 * 8];
      a1[i] = *(const bf16x8*)&Ac[r + sl1 * 8];
    }
#pragma unroll
    for (int j = 0; j < 2; ++j) {
      int r = (wn + j * 16 + rl) * 64;
      b0[j] = *(const bf16x8*)&Bc[r + sl0 * 8];
      b1[j] = *(const bf16x8*)&Bc[r + sl1 * 8];
    }
#pragma unroll
    for (int i = 0; i < 2; ++i)
#pragma unroll
      for (int j = 0; j < 2; ++j) {
        acc[i][j] = __builtin_amdgcn_mfma_f32_16x16x32_bf16(a0[i], b0[j],
                                                            acc[i][j], 0, 0, 0);
        acc[i][j] = __builtin_amdgcn_mfma_f32_16x16x32_bf16(a1[i], b1[j],
                                                            acc[i][j], 0, 0, 0);
      }
    __builtin_amdgcn_s_setprio(0);
    __syncthreads();
    cur ^= 1;
  }
  if (mode != 4) {
#pragma unroll
    for (int i = 0; i < 2; ++i) {
#pragma unroll
      for (int j = 0; j < 2; ++j) {
        int col = n0 + wn + j * 16 + rl;
        float bv = bias ? bias[col] : 0.f;
#pragma unroll
        for (int r2 = 0; r2 < 4; ++r2) {
          int row = m0 + wm + i * 16 + g * 4 + r2;
          size_t oi = (size_t)row * N + col;
          float v = acc[i][j][r2];
          if (mode == 0) {
            outb[oi] = f2bf(v + bv);
          } else if (mode == 1) {
            v += bv;
            float u = 0.7978845608028654f * (v + 0.044715f * v * v * v);
            outb[oi] = f2bf(0.5f * v * (1.f + tanhf(u)));
          } else {
            if (sk == 0) v += bv;
            atomicAdd(&outf[oi], v);
          }
        }
      }
    }
    return;
  }
  // ---- mode 4: fused qkv epilogue (tile = 64 tokens x 1 head dim-block) ----
  // stage acc (+bias) into cw[64][68]
#pragma unroll
  for (int i = 0; i < 2; ++i) {
#pragma unroll
    for (int j = 0; j < 2; ++j) {
      int col = wn + j * 16 + rl;
      float bv = bias[n0 + col];
#pragma unroll
      for (int r2 = 0; r2 < 4; ++r2)
        cw[(wm + i * 16 + g * 4 + r2) * 68 + col] = acc[i][j][r2] + bv;
    }
  }
  __syncthreads();
  int reg = n0 / DM;            // 0=q, 1=k, 2=v  (tiles never straddle regions)
  int h = (n0 % DM) / 64;       // head (tile = exactly one head)
  int b = m0 >> 10;             // SEQ=1024; whole tile same batch
  int t0 = m0 & (SEQ - 1);
  size_t bh = (size_t)(b * NH + h);
  if (reg < 2) {
    u16* dst = (reg == 0) ? qrp : krp;
    for (int t = tid; t < 2048; t += 256) {
      int rowc = t >> 5, cp = t & 31;   // row 0..63, u32-pair 0..31
      int d = 2 * cp;                   // even; pair (d, d+1) same rope class
      int tt = t0 + rowc;
      float x0 = cw[rowc * 68 + d];
      float x1 = cw[rowc * 68 + d + 1];
      float o0, o1;
      if (d < 32) {
        float y0 = cw[rowc * 68 + d + 32];
        float y1 = cw[rowc * 68 + d + 33];
        float c0 = 1.f, s0 = 0.f, c1 = 1.f, s1 = 0.f;
        if (d < 16) {
          c0 = ctab[tt * 16 + d];     s0 = stab[tt * 16 + d];
          c1 = ctab[tt * 16 + d + 1]; s1 = stab[tt * 16 + d + 1];
        }
        o0 = x0 * c0 - y0 * s0;
        o1 = x1 * c1 - y1 * s1;
      } else {
        int j = d - 32;
        float y0 = cw[rowc * 68 + j];
        float y1 = cw[rowc * 68 + j + 1];
        float c0 = 1.f, s0 = 0.f, c1 = 1.f, s1 = 0.f;
        if (j < 16) {
          c0 = ctab[tt * 16 + j];     s0 = stab[tt * 16 + j];
          c1 = ctab[tt * 16 + j + 1]; s1 = stab[tt * 16 + j + 1];
        }
        o0 = x0 * c0 + y0 * s0;
        o1 = x1 * c1 + y1 * s1;
      }
      u32 wv = (u32)f2bf(o0) | ((u32)f2bf(o1) << 16);
      *(u32*)&dst[(bh * SEQ + tt) * HD2 + d] = wv;
    }
  } else {
    // v: transposed write vT[bh][d][t], 2 tokens packed per u32
    for (int t = tid; t < 2048; t += 256) {
      int d = t >> 5, p = t & 31;       // d 0..63, token-pair 0..31
      int tt = t0 + 2 * p;
      u32 wv = (u32)f2bf(cw[(2 * p) * 68 + d]) |
               ((u32)f2bf(cw[(2 * p + 1) * 68 + d]) << 16);
      *(u32*)&vTp[(bh * HD2 + d) * SEQ + tt] = wv;
    }
  }
}

// ---------------- fallback GEMM (f32 B, on-the-fly cvt) — logits only --------
__global__ void k_gemm_f32b(const u16* __restrict__ A, const float* __restrict__ B,
                            float* __restrict__ outf, int M, int N, int K) {
  __shared__ u16 As[128 * 40];
  __shared__ u16 Bs[4 * 128 * 12];
  int tid = threadIdx.x;
  int wid = tid >> 6, lane = tid & 63;
  int rl = lane & 15, g = lane >> 4;
  int m0 = blockIdx.x * 128, n0 = blockIdx.y * 128;
  int wm = (wid >> 1) * 64, wn = (wid & 1) * 64;
  int ar = tid >> 2, ac = tid & 3;
  int bn = tid & 127, bq = tid >> 7;
  f32x4 acc[4][4] = {};
  int nK = K / 32;
  for (int kt = 0; kt < nK; ++kt) {
    __syncthreads();
    {
      const u16* ga = A + (size_t)(m0 + ar) * K + kt * 32 + ac * 8;
      *(uint4*)&As[ar * 40 + ac * 8] = *(const uint4*)ga;
      *(uint4*)&As[(ar + 64) * 40 + ac * 8] = *(const uint4*)(ga + (size_t)64 * K);
    }
    int col = n0 + bn;
#pragma unroll
    for (int r = 0; r < 4; ++r) {
      int kq = bq + 2 * r;
      int kk = kt * 32 + kq * 4;
      float f0 = 0.f, f1 = 0.f, f2v = 0.f, f3 = 0.f;
      if (col < N) {
        const float* gb = B + (size_t)kk * N + col;
        f0 = gb[0]; f1 = gb[(size_t)N]; f2v = gb[(size_t)2 * N]; f3 = gb[(size_t)3 * N];
      }
      uint2 wv;
      wv.x = (u32)f2bf(f0) | ((u32)f2bf(f1) << 16);
      wv.y = (u32)f2bf(f2v) | ((u32)f2bf(f3) << 16);
      *(uint2*)&Bs[(kq >> 1) * 1536 + bn * 12 + (kq & 1) * 4] = wv;
    }
    __syncthreads();
    bf16x8 af[4], bfr[4];
#pragma unroll
    for (int mt = 0; mt < 4; ++mt)
      af[mt] = *(const bf16x8*)&As[(wm + mt * 16 + rl) * 40 + g * 8];
#pragma unroll
    for (int nt = 0; nt < 4; ++nt) {
      const u16* p = &Bs[g * 1536 + (wn + nt * 16 + rl) * 12];
      union { bf16x8 v; uint2 u2[2]; } tmp;
      tmp.u2[0] = *(const uint2*)p;
      tmp.u2[1] = *(const uint2*)(p + 4);
      bfr[nt] = tmp.v;
    }
#pragma unroll
    for (int mt = 0; mt < 4; ++mt)
#pragma unroll
      for (int nt = 0; nt < 4; ++nt)
        acc[mt][nt] = __builtin_amdgcn_mfma_f32_16x16x32_bf16(af[mt], bfr[nt],
                                                              acc[mt][nt], 0, 0, 0);
  }
#pragma unroll
  for (int mt = 0; mt < 4; ++mt)
#pragma unroll
    for (int nt = 0; nt < 4; ++nt) {
      int col = n0 + wn + nt * 16 + rl;
      if (col >= N) continue;
#pragma unroll
      for (int r2 = 0; r2 < 4; ++r2) {
        int row = m0 + wm + mt * 16 + g * 4 + r2;
        outf[(size_t)row * N + col] = acc[mt][nt][r2];
      }
    }
}

extern "C" void kernel_launch(void* const* d_in, const int* in_sizes, int n_in,
                              void* d_out, int out_size, void* d_ws, size_t ws_size,
                              hipStream_t stream) {
  (void)in_sizes; (void)n_in; (void)out_size;
  const int*   idx  = (const int*)  d_in[0];
  const float* wte  = (const float*)d_in[1];
  const float* ln1g = (const float*)d_in[2];
  const float* ln1b = (const float*)d_in[3];
  const float* Wqkv = (const float*)d_in[4];
  const float* bqkv = (const float*)d_in[5];
  const float* Wo   = (const float*)d_in[6];
  const float* bo   = (const float*)d_in[7];
  const float* ln2g = (const float*)d_in[8];
  const float* ln2b = (const float*)d_in[9];
  const float* Wfc  = (const float*)d_in[10];
  const float* bfc  = (const float*)d_in[11];
  const float* Wp   = (const float*)d_in[12];
  const float* bp   = (const float*)d_in[13];
  const float* lnfg = (const float*)d_in[14];
  const float* lnfb = (const float*)d_in[15];
  const float* Wlm  = (const float*)d_in[16];
  float* out = (float*)d_out;

  // Scratch packed into d_out (all dead before the logits GEMM rewrites d_out).
  char* sb = (char*)d_out;
  size_t off = 0;
  auto alloc = [&](size_t bytes) {
    char* p = sb + off;
    off += (bytes + 255) & ~(size_t)255;
    return (void*)p;
  };
  float* xf  = (float*)alloc((size_t)BT * DM * 4);
  u16* h1b   = (u16*)alloc((size_t)BT * DM * 2);
  u16* h2b   = (u16*)alloc((size_t)BT * DM * 2);
  u16* qr    = (u16*)alloc((size_t)BT * DM * 2);
  u16* kr    = (u16*)alloc((size_t)BT * DM * 2);
  u16* vT    = (u16*)alloc((size_t)BT * DM * 2);
  u16* yb    = (u16*)alloc((size_t)BT * DM * 2);
  u16* hgel  = (u16*)alloc((size_t)BT * 4 * DM * 2);
  float* ctab = (float*)alloc((size_t)SEQ * 16 * 4);
  float* stab = (float*)alloc((size_t)SEQ * 16 * 4);
  // transposed bf16 weights (also dead before logits GEMM)
  u16* wqkvT = (u16*)alloc((size_t)NLAYER * 3 * DM * DM * 2);
  u16* woT   = (u16*)alloc((size_t)NLAYER * DM * DM * 2);
  u16* wfcT  = (u16*)alloc((size_t)NLAYER * 4 * DM * DM * 2);
  u16* wpT   = (u16*)alloc((size_t)NLAYER * 4 * DM * DM * 2);

  // Wlm^T (77 MB) must survive the logits GEMM -> d_ws if it fits.
  size_t wlmT_bytes = (size_t)NVOCAB * DM * 2;
  size_t xlnf_bytes = (size_t)BT * DM * 2;
  bool fast_lm = ws_size >= wlmT_bytes + xlnf_bytes + 512;
  u16* wlmT = (u16*)d_ws;
  u16* xlnf = fast_lm ? (u16*)((char*)d_ws + ((wlmT_bytes + 255) & ~(size_t)255))
                      : (u16*)d_ws;

  // ---- weight conversion + trig tables ----
  k_trig<<<(SEQ * 16) / 256, 256, 0, stream>>>(ctab, stab);
  for (int l = 0; l < NLAYER; ++l) {
    k_cvtT<<<dim3((3 * DM + 63) / 64, DM / 64), 256, 0, stream>>>(
        Wqkv + (size_t)l * DM * 3 * DM, wqkvT + (size_t)l * 3 * DM * DM, DM, 3 * DM);
    k_cvtT<<<dim3(DM / 64, DM / 64), 256, 0, stream>>>(
        Wo + (size_t)l * DM * DM, woT + (size_t)l * DM * DM, DM, DM);
    k_cvtT<<<dim3((4 * DM) / 64, DM / 64), 256, 0, stream>>>(
        Wfc + (size_t)l * DM * 4 * DM, wfcT + (size_t)l * 4 * DM * DM, DM, 4 * DM);
    k_cvtT<<<dim3(DM / 64, (4 * DM) / 64), 256, 0, stream>>>(
        Wp + (size_t)l * 4 * DM * DM, wpT + (size_t)l * 4 * DM * DM, 4 * DM, DM);
  }
  if (fast_lm)
    k_cvtT<<<dim3((NVOCAB + 63) / 64, DM / 64), 256, 0, stream>>>(Wlm, wlmT, DM, NVOCAB);

  k_embed<<<BT, 256, 0, stream>>>(idx, wte, xf);
  for (int l = 0; l < NLAYER; ++l) {
    k_ln<<<BT, 256, 0, stream>>>(xf, ln1g + l * DM, ln1b + l * DM,
                                 ln2g + l * DM, ln2b + l * DM, h1b, h2b);
    // fused qkv GEMM + bias + rope + v-transpose
    k_gemm64<<<dim3((BT / 64) * (3 * DM / 64), 1), 256, 0, stream>>>(
        h1b, wqkvT + (size_t)l * 3 * DM * DM, bqkv + (size_t)l * 3 * DM,
        nullptr, nullptr, BT, 3 * DM, DM, BT / 64, 4, ctab, stab, qr, kr, vT);
    k_attn<<<dim3(SEQ / 64, 2 * NH), 256, 0, stream>>>(qr, kr, vT, yb);
    k_gemm64<<<dim3((BT / 64) * (DM / 64), 2), 256, 0, stream>>>(
        yb, woT + (size_t)l * DM * DM, bo + (size_t)l * DM,
        nullptr, xf, BT, DM, DM, BT / 64, 2, nullptr, nullptr, nullptr, nullptr, nullptr);
    k_gemm64<<<dim3((BT / 64) * (4 * DM / 64), 1), 256, 0, stream>>>(
        h2b, wfcT + (size_t)l * 4 * DM * DM, bfc + (size_t)l * 4 * DM,
        hgel, nullptr, BT, 4 * DM, DM, BT / 64, 1, nullptr, nullptr, nullptr, nullptr, nullptr);
    k_gemm64<<<dim3((BT / 64) * (DM / 64), 4), 256, 0, stream>>>(
        hgel, wpT + (size_t)l * 4 * DM * DM, bp + (size_t)l * DM,
        nullptr, xf, BT, DM, 4 * DM, BT / 64, 2, nullptr, nullptr, nullptr, nullptr, nullptr);
  }
  k_ln<<<BT, 256, 0, stream>>>(xf, lnfg, lnfb, nullptr, nullptr, xlnf, nullptr);
  if (fast_lm) {
    int nt = (NVOCAB + 127) / 128;
    k_logits<<<(BT / 128) * nt, 256, 0, stream>>>(
        xlnf, wlmT, out, BT, NVOCAB, DM, BT / 128);
  } else {
    k_gemm_f32b<<<dim3(BT / 128, (NVOCAB + 127) / 128), 256, 0, stream>>>(
        xlnf, Wlm, out, BT, NVOCAB, DM);
  }
}